// Round 12
// baseline (85400.525 us; speedup 1.0000x reference)
//
#include <hip/hip_runtime.h>
#include <hip/hip_bf16.h>

// HRM-LM on MI355X — 2-plane batch-split pipeline, masterless sync.
// Batch rows 0-3 = plane A, 4-7 = plane B (independent recurrences, shared
// LDS-resident weights). 128 worker WGs, no master. Per round per plane:
// waitB(gate counters) -> zero next-parity stats -> stage h replica (16B sc1
// batched) -> GEMM own 24/18 cols -> fp32-atomic-accumulate LN stats into
// 8 replica columns [row][rep] -> drain -> bump sharded stats counter ->
// poll counters (8-lane) -> read 64B row (all 8 reps) -> mean/rsqrt local ->
// gate own cols -> write 4 h replicas -> drain -> bump gate counter.
// xi = XW (x@Wi_x per token, local) + h_h@Wi_h. Logits: deferred bf16 MFMA.

#define NWG 128
#define NTH 256
#define EPSV 1e-5f

typedef __attribute__((ext_vector_type(4))) float f32x4;
typedef __attribute__((ext_vector_type(8))) short short8;
typedef unsigned long long u64;

struct PArgs {
  const int* ids; const float* emb; const float* lng; const float* lnb;
  const float* lWi; const float* lbi; const float* lWh; const float* lbh;
  const float* llig; const float* llib; const float* llhg; const float* llhb;
  const float* hWi; const float* hbi; const float* hWh; const float* hbh;
  const float* hlig; const float* hlib; const float* hlhg; const float* hlhb;
  int* cnt; int* scnt; float* statsA; float* hlR; float* hhR;
  __hip_bfloat16* hist; float* WiT; float* hWiT; float* hWhT;
};

__device__ __forceinline__ float sigm(float x) { return 1.f / (1.f + __expf(-x)); }
__device__ __forceinline__ float tanh_f(float x) {
  x = fminf(15.f, fmaxf(-15.f, x));
  float e = __expf(2.f * x);
  return (e - 1.f) / (e + 1.f);
}
__device__ __forceinline__ int aldi(const int* p) {
  return __hip_atomic_load(p, __ATOMIC_RELAXED, __HIP_MEMORY_SCOPE_AGENT);
}
__device__ __forceinline__ void astu(u64* p, u64 v) {
  __hip_atomic_store(p, v, __ATOMIC_RELAXED, __HIP_MEMORY_SCOPE_AGENT);
}
__device__ __forceinline__ void ast(float* p, float v) {
  __hip_atomic_store(p, v, __ATOMIC_RELAXED, __HIP_MEMORY_SCOPE_AGENT);
}
// batched 16B sc1 loads; s_waitcnt INSIDE asm -> outputs valid at asm exit
__device__ __forceinline__ void ald4x4(const float* p0, const float* p1,
                                       const float* p2, const float* p3,
                                       float4& a, float4& b, float4& c, float4& d) {
  asm volatile(
      "global_load_dwordx4 %0, %4, off sc1\n\t"
      "global_load_dwordx4 %1, %5, off sc1\n\t"
      "global_load_dwordx4 %2, %6, off sc1\n\t"
      "global_load_dwordx4 %3, %7, off sc1\n\t"
      "s_waitcnt vmcnt(0)"
      : "=&v"(a), "=&v"(b), "=&v"(c), "=&v"(d)
      : "v"(p0), "v"(p1), "v"(p2), "v"(p3)
      : "memory");
}
__device__ __forceinline__ void ald4x3(const float* p0, const float* p1,
                                       const float* p2,
                                       float4& a, float4& b, float4& c) {
  asm volatile(
      "global_load_dwordx4 %0, %3, off sc1\n\t"
      "global_load_dwordx4 %1, %4, off sc1\n\t"
      "global_load_dwordx4 %2, %5, off sc1\n\t"
      "s_waitcnt vmcnt(0)"
      : "=&v"(a), "=&v"(b), "=&v"(c)
      : "v"(p0), "v"(p1), "v"(p2)
      : "memory");
}

__global__ void __launch_bounds__(NTH) hrm_recur(PArgs P) {
  __shared__ float WhS[24 * 1024];   // low_Wh slice [c][k]
  __shared__ float Bb[8 * 1024];     // staged operand; rows 0-3 = A, 4-7 = B
  __shared__ float XW[24 * 8];       // x @ Wi_x for own 24 cols (per token)
  __shared__ float xiNs[24 * 8];     // normalized xi, kept across inner iters
  __shared__ float stg[2 * 24 * 8];  // raw GEMM outputs (both planes coexist)
  __shared__ float sred[96];         // (m, rs) per (set,g,b)
  __shared__ float xm[8], xrs[8];
  __shared__ int idsh[8];
  __shared__ int okf;

  const int tid = threadIdx.x;
  const int wg = blockIdx.x;
  const int ks = tid & 31, cg = tid >> 5;
  const int lj8 = wg * 8, lj6 = wg * 6;
  const int rep = wg & 3;

  // ---- sync-B: cumulative gate counters (8 lanes, one load each) ----
  auto waitB = [&](int pl, int target) -> bool {
    if (tid < 64) {
      bool active = tid < 8;
      const int* cp = P.cnt + pl * 256 + (size_t)(active ? tid : 0) * 32;
      int lim = 1 << 22;
      for (;;) {
        int v = active ? aldi(cp) : 0;
        int sum = v;
        sum += __shfl_xor(sum, 1);
        sum += __shfl_xor(sum, 2);
        sum += __shfl_xor(sum, 4);
        int total = __shfl(sum, 0);
        if (total >= target) break;
        if (--lim == 0) break;
        __builtin_amdgcn_s_sleep(2);
      }
      if (tid == 0) okf = (lim != 0) ? 1 : 0;
    }
    __syncthreads();
    return okf != 0;
  };
  auto gate_commit = [&](int pl) {
    asm volatile("s_waitcnt vmcnt(0)" ::: "memory");
    if (tid == 0)
      __hip_atomic_fetch_add(P.cnt + pl * 256 + (size_t)(wg & 7) * 32, 1,
                             __ATOMIC_RELAXED, __HIP_MEMORY_SCOPE_AGENT);
  };

  // ---- stats: fp32 atomic accumulate into [pl][par][row24][rep8][2] ----
  auto zeroStats = [&](int pl, int pz) {   // zero next parity (wg<8: own rep)
    if (wg < 8 && tid < 24)
      astu((u64*)(P.statsA + (((size_t)(pl * 2 + pz) * 24 + tid) * 16) + wg * 2), 0ull);
  };
  auto stats_put = [&](int pl, int par, int set, int perg) {
    if (tid < 12) {
      int g = tid >> 2, bq = tid & 3;
      float s1 = 0.f, s2 = 0.f;
      for (int jj = 0; jj < perg; ++jj) {
        float v = stg[set * 192 + (g * perg + jj) * 8 + pl * 4 + bq];
        s1 += v; s2 += v * v;
      }
      int row = set * 12 + g * 4 + bq;
      float* ap = P.statsA + (((size_t)(pl * 2 + par) * 24 + row) * 16) + (wg & 7) * 2;
      unsafeAtomicAdd(ap, s1);
      unsafeAtomicAdd(ap + 1, s2);
    }
  };
  auto statsCommit = [&](int pl) {
    asm volatile("s_waitcnt vmcnt(0)" ::: "memory");
    if (tid == 0)
      __hip_atomic_fetch_add(P.scnt + pl * 256 + (size_t)(wg & 7) * 32, 1,
                             __ATOMIC_RELAXED, __HIP_MEMORY_SCOPE_AGENT);
  };
  // poll stats counters, then read own rows (all 8 reps = 64B) and finish LN
  auto pollStats = [&](int pl, int r, bool full, float invD) -> bool {
    if (tid < 64) {
      bool active = tid < 8;
      const int* cp = P.scnt + pl * 256 + (size_t)(active ? tid : 0) * 32;
      int lim = 1 << 22;
      for (;;) {
        int v = active ? aldi(cp) : 0;
        int sum = v;
        sum += __shfl_xor(sum, 1);
        sum += __shfl_xor(sum, 2);
        sum += __shfl_xor(sum, 4);
        int total = __shfl(sum, 0);
        if (total >= NWG * r) break;
        if (--lim == 0) break;
        __builtin_amdgcn_s_sleep(1);
      }
      if (tid == 0) okf = (lim != 0) ? 1 : 0;
    }
    __syncthreads();
    if (!okf) return false;
    int base_row = full ? 0 : 12;
    int n = full ? 24 : 12;
    if (tid < n) {
      int row = base_row + tid;
      const float* rp = P.statsA + (((size_t)(pl * 2 + (r & 1)) * 24 + row) * 16);
      float4 a, b, c, d;
      ald4x4(rp, rp + 4, rp + 8, rp + 12, a, b, c, d);
      float s1 = a.x + a.z + b.x + b.z + c.x + c.z + d.x + d.z;
      float s2 = a.y + a.w + b.y + b.w + c.y + c.w + d.y + d.w;
      float m = s1 * invD;
      float rs = rsqrtf(s2 * invD - m * m + EPSV);
      int set = row / 12, rem = row % 12, g = rem >> 2, bq = rem & 3;
      int b2 = pl * 4 + bq;
      sred[set * 48 + g * 16 + b2 * 2] = m;
      sred[set * 48 + g * 16 + b2 * 2 + 1] = rs;
    }
    __syncthreads();
    return true;
  };

  auto stage_hl = [&](int pl) {
    const float* base = P.hlR + (size_t)rep * 8192 + (size_t)pl * 4096 + tid * 4;
    float4 t0, t1, t2, t3;
    ald4x4(base + 0 * 1024, base + 1 * 1024, base + 2 * 1024, base + 3 * 1024,
           t0, t1, t2, t3);
    float* db = &Bb[pl * 4096 + tid * 4];
    *(float4*)&db[0 * 1024] = t0; *(float4*)&db[1 * 1024] = t1;
    *(float4*)&db[2 * 1024] = t2; *(float4*)&db[3 * 1024] = t3;
  };
  auto stage_hh = [&](int pl) {
    const float* base = P.hhR + (size_t)rep * 6144 + (size_t)pl * 3072;
    int bi[3], ki[3];
    #pragma unroll
    for (int i = 0; i < 3; ++i) {
      int c = i * 256 + tid; int bq = c / 192; int k = (c - bq * 192) * 4;
      bi[i] = bq; ki[i] = k;
    }
    float4 t0, t1, t2;
    ald4x3(base + bi[0] * 768 + ki[0], base + bi[1] * 768 + ki[1],
           base + bi[2] * 768 + ki[2], t0, t1, t2);
    *(float4*)&Bb[(pl * 4 + bi[0]) * 1024 + ki[0]] = t0;
    *(float4*)&Bb[(pl * 4 + bi[1]) * 1024 + ki[1]] = t1;
    *(float4*)&Bb[(pl * 4 + bi[2]) * 1024 + ki[2]] = t2;
  };

  auto gemm_lowh = [&](int pl, float (&acc)[3][4]) {
    const int c0 = cg * 3;
    const float* w0p = &WhS[(c0 + 0) * 1024];
    const float* w1p = &WhS[(c0 + 1) * 1024];
    const float* w2p = &WhS[(c0 + 2) * 1024];
    const float* hb = &Bb[pl * 4096];
    #pragma unroll
    for (int i = 0; i < 8; ++i) {
      int k = i * 128 + ks * 4;
      float4 w0 = *(const float4*)&w0p[k];
      float4 w1 = *(const float4*)&w1p[k];
      float4 w2 = *(const float4*)&w2p[k];
      #pragma unroll
      for (int bq = 0; bq < 4; ++bq) {
        float4 h = *(const float4*)&hb[bq * 1024 + k];
        acc[0][bq] += w0.x*h.x + w0.y*h.y + w0.z*h.z + w0.w*h.w;
        acc[1][bq] += w1.x*h.x + w1.y*h.y + w1.z*h.z + w1.w*h.w;
        acc[2][bq] += w2.x*h.x + w2.y*h.y + w2.z*h.z + w2.w*h.w;
      }
    }
  };
  auto gemm_xih = [&](int pl, float (&acc)[3][4]) {   // K=768 over Bb=hh
    const float* wp[3];
    #pragma unroll
    for (int cc = 0; cc < 3; ++cc) {
      int c = cg * 3 + cc; int g = c >> 3, jj = c & 7;
      wp[cc] = P.WiT + ((size_t)g * 1024 + lj8 + jj) * 1536 + 768;
    }
    const float* hb = &Bb[pl * 4096];
    #pragma unroll
    for (int i = 0; i < 6; ++i) {
      int k = i * 128 + ks * 4;
      float4 w0 = *(const float4*)&wp[0][k];
      float4 w1 = *(const float4*)&wp[1][k];
      float4 w2 = *(const float4*)&wp[2][k];
      #pragma unroll
      for (int bq = 0; bq < 4; ++bq) {
        float4 h = *(const float4*)&hb[bq * 1024 + k];
        acc[0][bq] += w0.x*h.x + w0.y*h.y + w0.z*h.z + w0.w*h.w;
        acc[1][bq] += w1.x*h.x + w1.y*h.y + w1.z*h.z + w1.w*h.w;
        acc[2][bq] += w2.x*h.x + w2.y*h.y + w2.z*h.z + w2.w*h.w;
      }
    }
  };
  auto gemm_hxi = [&](int pl, float (&acc)[3][4]) {  // K=1024 over Bb=hl
    if (cg >= 6) return;
    const float* wp[3];
    #pragma unroll
    for (int cc = 0; cc < 3; ++cc) {
      int c = cg * 3 + cc; int g = c / 6, jj = c % 6;
      wp[cc] = P.hWiT + ((size_t)g * 768 + lj6 + jj) * 1024;
    }
    const float* hb = &Bb[pl * 4096];
    #pragma unroll
    for (int i = 0; i < 8; ++i) {
      int k = i * 128 + ks * 4;
      float4 w0 = *(const float4*)&wp[0][k];
      float4 w1 = *(const float4*)&wp[1][k];
      float4 w2 = *(const float4*)&wp[2][k];
      #pragma unroll
      for (int bq = 0; bq < 4; ++bq) {
        float4 h = *(const float4*)&hb[bq * 1024 + k];
        acc[0][bq] += w0.x*h.x + w0.y*h.y + w0.z*h.z + w0.w*h.w;
        acc[1][bq] += w1.x*h.x + w1.y*h.y + w1.z*h.z + w1.w*h.w;
        acc[2][bq] += w2.x*h.x + w2.y*h.y + w2.z*h.z + w2.w*h.w;
      }
    }
  };
  auto gemm_hhh = [&](int pl, float (&acc)[3][4]) {  // K=768 over Bb=hh
    if (cg >= 6) return;
    const float* wp[3];
    #pragma unroll
    for (int cc = 0; cc < 3; ++cc) {
      int c = cg * 3 + cc; int g = c / 6, jj = c % 6;
      wp[cc] = P.hWhT + ((size_t)g * 768 + lj6 + jj) * 768;
    }
    const float* hb = &Bb[pl * 4096];
    #pragma unroll
    for (int i = 0; i < 6; ++i) {
      int k = i * 128 + ks * 4;
      float4 w0 = *(const float4*)&wp[0][k];
      float4 w1 = *(const float4*)&wp[1][k];
      float4 w2 = *(const float4*)&wp[2][k];
      #pragma unroll
      for (int bq = 0; bq < 4; ++bq) {
        float4 h = *(const float4*)&hb[bq * 1024 + k];
        acc[0][bq] += w0.x*h.x + w0.y*h.y + w0.z*h.z + w0.w*h.w;
        acc[1][bq] += w1.x*h.x + w1.y*h.y + w1.z*h.z + w1.w*h.w;
        acc[2][bq] += w2.x*h.x + w2.y*h.y + w2.z*h.z + w2.w*h.w;
      }
    }
  };

  auto redstage = [&](int pl, float (&acc)[3][4], int set, const float* bias,
                      int dim, int perg, int jb, bool addXW) {
    #pragma unroll
    for (int cc = 0; cc < 3; ++cc)
      #pragma unroll
      for (int bq = 0; bq < 4; ++bq) {
        float v = acc[cc][bq];
        #pragma unroll
        for (int m = 1; m < 32; m <<= 1) v += __shfl_xor(v, m, 64);
        acc[cc][bq] = v;
      }
    if ((tid & 31) == 0) {
      int cgl = tid >> 5;
      #pragma unroll
      for (int cc = 0; cc < 3; ++cc) {
        int c = cgl * 3 + cc;
        if (c < perg * 3) {
          int g = (perg == 8) ? (c >> 3) : (c / 6);
          int jj = (perg == 8) ? (c & 7) : (c % 6);
          float bs = bias[g * dim + jb + jj];
          #pragma unroll
          for (int bq = 0; bq < 4; ++bq) {
            float v = acc[cc][bq] + bs;
            if (addXW) v += XW[c * 8 + pl * 4 + bq];
            stg[set * 192 + c * 8 + pl * 4 + bq] = v;
          }
        }
      }
    }
  };

  auto gate_low = [&](int pl, bool isA) {
    if (tid < 32) {
      int jj = tid & 7, bq = tid >> 3; int b = pl * 4 + bq; int j = lj8 + jj;
      float xin[3], hin[3];
      #pragma unroll
      for (int g = 0; g < 3; ++g) {
        int c = g * 8 + jj;
        if (isA) {
          float m = sred[g * 16 + b * 2], rs = sred[g * 16 + b * 2 + 1];
          float v = (stg[c * 8 + b] - m) * rs * P.llig[g * 1024 + j] + P.llib[g * 1024 + j];
          xiNs[c * 8 + b] = v; xin[g] = v;
        } else {
          xin[g] = xiNs[c * 8 + b];
        }
        float m2 = sred[48 + g * 16 + b * 2], rs2 = sred[48 + g * 16 + b * 2 + 1];
        hin[g] = (stg[192 + c * 8 + b] - m2) * rs2 * P.llhg[g * 1024 + j] + P.llhb[g * 1024 + j];
      }
      float rg = sigm(xin[0] + hin[0]);
      float zg = sigm(xin[1] + hin[1]);
      float ng = tanh_f(xin[2] + rg * hin[2]);
      float hold = Bb[b * 1024 + j];
      float hv = (1.f - zg) * ng + zg * hold;
      #pragma unroll
      for (int rp = 0; rp < 4; ++rp) ast(&P.hlR[rp * 8192 + b * 1024 + j], hv);
    }
  };

  auto gate_high = [&](int pl, int t, int nn) {
    if (tid < 24) {
      int jj = tid % 6, bq = tid / 6; int b = pl * 4 + bq; int j = lj6 + jj;
      float xin[3], hin[3];
      #pragma unroll
      for (int g = 0; g < 3; ++g) {
        int c = g * 6 + jj;
        float m = sred[g * 16 + b * 2], rs = sred[g * 16 + b * 2 + 1];
        xin[g] = (stg[c * 8 + b] - m) * rs * P.hlig[g * 768 + j] + P.hlib[g * 768 + j];
        float m2 = sred[48 + g * 16 + b * 2], rs2 = sred[48 + g * 16 + b * 2 + 1];
        hin[g] = (stg[192 + c * 8 + b] - m2) * rs2 * P.hlhg[g * 768 + j] + P.hlhb[g * 768 + j];
      }
      float rg = sigm(xin[0] + hin[0]);
      float zg = sigm(xin[1] + hin[1]);
      float ng = tanh_f(xin[2] + rg * hin[2]);
      float hold = Bb[b * 1024 + j];
      float hv = (1.f - zg) * ng + zg * hold;
      #pragma unroll
      for (int rp = 0; rp < 4; ++rp) ast(&P.hhR[rp * 6144 + b * 768 + j], hv);
      if (nn == 2) P.hist[((size_t)t * 8 + b) * 768 + j] = __float2bfloat16(hv);
    }
  };

  // per token: LN(x) stats + XW = LN(x) @ Wi_x (own 24 cols, all 8 b, local)
  auto xfun = [&](int tt) {
    int bq = tid >> 5, u = tid & 31;
    if (tid < 8) idsh[tid] = P.ids[tid * 256 + tt];
    int id = P.ids[bq * 256 + tt];
    const float* e = P.emb + (size_t)id * 768;
    float s1 = 0.f, s2 = 0.f;
    #pragma unroll
    for (int q = 0; q < 24; q += 4) {
      float4 v = *(const float4*)&e[u * 24 + q];
      s1 += v.x + v.y + v.z + v.w;
      s2 += v.x*v.x + v.y*v.y + v.z*v.z + v.w*v.w;
    }
    #pragma unroll
    for (int m = 1; m < 32; m <<= 1) { s1 += __shfl_xor(s1, m, 64); s2 += __shfl_xor(s2, m, 64); }
    if (u == 0) { float mm = s1 / 768.f; xm[bq] = mm; xrs[bq] = rsqrtf(s2 / 768.f - mm * mm + EPSV); }
    __syncthreads();
    float acc[3][8] = {};
    const float* wp[3];
    #pragma unroll
    for (int cc = 0; cc < 3; ++cc) {
      int c = cg * 3 + cc; int g = c >> 3, jj = c & 7;
      wp[cc] = P.WiT + ((size_t)g * 1024 + lj8 + jj) * 1536;
    }
    int idv[8];
    #pragma unroll
    for (int bb = 0; bb < 8; ++bb) idv[bb] = idsh[bb];
    #pragma unroll
    for (int i = 0; i < 6; ++i) {
      int k = i * 128 + ks * 4;
      float4 w0 = *(const float4*)&wp[0][k];
      float4 w1 = *(const float4*)&wp[1][k];
      float4 w2 = *(const float4*)&wp[2][k];
      float4 gam = *(const float4*)&P.lng[k];
      float4 bet = *(const float4*)&P.lnb[k];
      #pragma unroll
      for (int bb = 0; bb < 8; ++bb) {
        float4 xv = *(const float4*)&P.emb[(size_t)idv[bb] * 768 + k];
        float4 xn;
        xn.x = (xv.x - xm[bb]) * xrs[bb] * gam.x + bet.x;
        xn.y = (xv.y - xm[bb]) * xrs[bb] * gam.y + bet.y;
        xn.z = (xv.z - xm[bb]) * xrs[bb] * gam.z + bet.z;
        xn.w = (xv.w - xm[bb]) * xrs[bb] * gam.w + bet.w;
        acc[0][bb] += w0.x*xn.x + w0.y*xn.y + w0.z*xn.z + w0.w*xn.w;
        acc[1][bb] += w1.x*xn.x + w1.y*xn.y + w1.z*xn.z + w1.w*xn.w;
        acc[2][bb] += w2.x*xn.x + w2.y*xn.y + w2.z*xn.z + w2.w*xn.w;
      }
    }
    #pragma unroll
    for (int cc = 0; cc < 3; ++cc)
      #pragma unroll
      for (int bb = 0; bb < 8; ++bb) {
        float v = acc[cc][bb];
        #pragma unroll
        for (int m = 1; m < 32; m <<= 1) v += __shfl_xor(v, m, 64);
        acc[cc][bb] = v;
      }
    if ((tid & 31) == 0) {
      int cgl = tid >> 5;
      #pragma unroll
      for (int cc = 0; cc < 3; ++cc)
        #pragma unroll
        for (int bb = 0; bb < 8; ++bb)
          XW[(cgl * 3 + cc) * 8 + bb] = acc[cc][bb];
    }
    __syncthreads();
  };

  // =================== prologue: weight transposes ===================
  #pragma unroll 1
  for (int g = 0; g < 3; ++g)
    for (int it = 0; it < 6; ++it) {   // low_Wi -> WiT[g][j][k]
      int k = it * 256 + tid;
      const float* src = P.lWi + ((size_t)g * 1536 + k) * 1024 + lj8;
      float4 v0 = *(const float4*)src; float4 v1 = *(const float4*)(src + 4);
      float vv[8] = {v0.x, v0.y, v0.z, v0.w, v1.x, v1.y, v1.z, v1.w};
      for (int jj = 0; jj < 8; ++jj)
        P.WiT[((size_t)g * 1024 + lj8 + jj) * 1536 + k] = vv[jj];
    }
  #pragma unroll 1
  for (int g = 0; g < 3; ++g)
    for (int it = 0; it < 4; ++it) {   // high_Wi -> hWiT[g][j][k]
      int k = it * 256 + tid;
      const float* src = P.hWi + ((size_t)g * 1024 + k) * 768 + lj6;
      float2 a = *(const float2*)src, b2v = *(const float2*)(src + 2), c2v = *(const float2*)(src + 4);
      float vv[6] = {a.x, a.y, b2v.x, b2v.y, c2v.x, c2v.y};
      for (int jj = 0; jj < 6; ++jj)
        P.hWiT[((size_t)g * 768 + lj6 + jj) * 1024 + k] = vv[jj];
    }
  #pragma unroll 1
  for (int g = 0; g < 3; ++g)
    for (int it = 0; it < 3; ++it) {   // high_Wh -> hWhT[g][j][k]
      int k = it * 256 + tid;
      const float* src = P.hWh + ((size_t)g * 768 + k) * 768 + lj6;
      float2 a = *(const float2*)src, b2v = *(const float2*)(src + 2), c2v = *(const float2*)(src + 4);
      float vv[6] = {a.x, a.y, b2v.x, b2v.y, c2v.x, c2v.y};
      for (int jj = 0; jj < 6; ++jj)
        P.hWhT[((size_t)g * 768 + lj6 + jj) * 768 + k] = vv[jj];
    }
  #pragma unroll 1
  for (int g = 0; g < 3; ++g)
    for (int it = 0; it < 4; ++it) {   // low_Wh slice -> LDS
      int k = it * 256 + tid;
      const float* src = P.lWh + ((size_t)g * 1024 + k) * 1024 + lj8;
      float4 v0 = *(const float4*)src; float4 v1 = *(const float4*)(src + 4);
      float vv[8] = {v0.x, v0.y, v0.z, v0.w, v1.x, v1.y, v1.z, v1.w};
      for (int jj = 0; jj < 8; ++jj) WhS[(g * 8 + jj) * 1024 + k] = vv[jj];
    }
  __syncthreads();
  xfun(0);

  // =================== main recurrence (2-plane pipeline) ===================
  int r = 1;
  bool alive = true;
  #pragma unroll 1
  for (int t = 0; t < 256 && alive; ++t) {
    #pragma unroll 1
    for (int nn = 0; nn < 3 && alive; ++nn) {
      // ---- round A: xi (XW + hh@Wi_h) + lowh ----
      {
        #pragma unroll 1
        for (int pl = 0; pl < 2; ++pl) {
          alive = waitB(pl, NWG * (r - 1)); if (!alive) break;
          zeroStats(pl, (r + 1) & 1);
          stage_hh(pl); __syncthreads();
          float aX[3][4] = {};
          gemm_xih(pl, aX);
          redstage(pl, aX, 0, P.lbi, 1024, 8, lj8, true);
          __syncthreads();
          stage_hl(pl); __syncthreads();
          float aH[3][4] = {};
          gemm_lowh(pl, aH);
          redstage(pl, aH, 1, P.lbh, 1024, 8, lj8, false);
          __syncthreads();
          stats_put(pl, r & 1, 0, 8); stats_put(pl, r & 1, 1, 8);
          statsCommit(pl);
        }
        if (!alive) break;
        #pragma unroll 1
        for (int pl = 0; pl < 2; ++pl) {
          alive = pollStats(pl, r, true, 1.f / 1024.f); if (!alive) break;
          gate_low(pl, true);
          gate_commit(pl);
        }
        if (!alive) break;
        ++r;
      }
      // ---- inner iterations 2..5 ----
      #pragma unroll 1
      for (int it = 1; it < 5 && alive; ++it) {
        #pragma unroll 1
        for (int pl = 0; pl < 2; ++pl) {
          alive = waitB(pl, NWG * (r - 1)); if (!alive) break;
          zeroStats(pl, (r + 1) & 1);
          stage_hl(pl); __syncthreads();
          float a2[3][4] = {};
          gemm_lowh(pl, a2);
          redstage(pl, a2, 1, P.lbh, 1024, 8, lj8, false);
          __syncthreads();
          stats_put(pl, r & 1, 1, 8);
          statsCommit(pl);
        }
        if (!alive) break;
        #pragma unroll 1
        for (int pl = 0; pl < 2; ++pl) {
          alive = pollStats(pl, r, false, 1.f / 1024.f); if (!alive) break;
          gate_low(pl, false);
          gate_commit(pl);
        }
        if (!alive) break;
        ++r;
      }
      if (!alive) break;
      // ---- high GRU round ----
      {
        #pragma unroll 1
        for (int pl = 0; pl < 2; ++pl) {
          alive = waitB(pl, NWG * (r - 1)); if (!alive) break;
          zeroStats(pl, (r + 1) & 1);
          stage_hl(pl); __syncthreads();
          float aX[3][4] = {};
          gemm_hxi(pl, aX);
          redstage(pl, aX, 0, P.hbi, 768, 6, lj6, false);
          __syncthreads();
          stage_hh(pl); __syncthreads();
          float aH[3][4] = {};
          gemm_hhh(pl, aH);
          redstage(pl, aH, 1, P.hbh, 768, 6, lj6, false);
          __syncthreads();
          stats_put(pl, r & 1, 0, 6); stats_put(pl, r & 1, 1, 6);
          statsCommit(pl);
        }
        if (!alive) break;
        #pragma unroll 1
        for (int pl = 0; pl < 2; ++pl) {
          alive = pollStats(pl, r, true, 1.f / 768.f); if (!alive) break;
          gate_high(pl, t, nn);
          gate_commit(pl);
        }
        if (!alive) break;
        ++r;
        if (nn == 2 && t < 255) { __syncthreads(); xfun(t + 1); }
      }
    }
  }
}

// =================== Wout transpose + bf16 convert ===================
__global__ void __launch_bounds__(256) wout_t(const float* __restrict__ W,
                                              __hip_bfloat16* __restrict__ WT) {
  __shared__ float T[64][65];
  int n0 = blockIdx.x * 64, k0 = blockIdx.y * 64;
  int tid = threadIdx.x;
  int lane16 = tid & 15, grp = tid >> 4;
  #pragma unroll
  for (int i = 0; i < 4; ++i) {
    int kl = i * 16 + grp; int nl = lane16 * 4;
    float4 v = *(const float4*)&W[(size_t)(k0 + kl) * 32000 + n0 + nl];
    T[kl][nl] = v.x; T[kl][nl + 1] = v.y; T[kl][nl + 2] = v.z; T[kl][nl + 3] = v.w;
  }
  __syncthreads();
  #pragma unroll
  for (int i = 0; i < 4; ++i) {
    int nl = i * 16 + grp; int kl = lane16 * 4;
    union { ushort4 v; __hip_bfloat16 h[4]; } u;
    for (int q = 0; q < 4; ++q) u.h[q] = __float2bfloat16(T[kl + q][nl]);
    *(ushort4*)&WT[(size_t)(n0 + nl) * 768 + k0 + kl] = u.v;
  }
}

// =================== logits GEMM: [2048,768] x [768,32000]^T-stored ===================
__global__ void __launch_bounds__(256) logits_gemm(const __hip_bfloat16* __restrict__ Ah,
                                                   const __hip_bfloat16* __restrict__ Bt,
                                                   const float* __restrict__ bias,
                                                   float* __restrict__ out) {
  __shared__ short As[128 * 64];
  __shared__ short Bs[128 * 64];
  int m0 = blockIdx.y * 128, n0 = blockIdx.x * 128;
  int tid = threadIdx.x, lane = tid & 63, w = tid >> 6;
  int wr = w >> 1, wc = w & 1;
  int r16 = lane & 15, khalf = (lane >> 4) * 8;
  f32x4 acc[4][4];
  #pragma unroll
  for (int i = 0; i < 4; ++i)
    #pragma unroll
    for (int j = 0; j < 4; ++j)
      #pragma unroll
      for (int q = 0; q < 4; ++q) acc[i][j][q] = 0.f;

  for (int kt = 0; kt < 12; ++kt) {
    int k0 = kt * 64;
    __syncthreads();
    #pragma unroll
    for (int it = 0; it < 4; ++it) {
      int f = it * 2048 + tid * 8; int row = f >> 6, col = f & 63;
      *(uint4*)&As[f] = *(const uint4*)&Ah[(size_t)(m0 + row) * 768 + k0 + col];
      *(uint4*)&Bs[f] = *(const uint4*)&Bt[(size_t)(n0 + row) * 768 + k0 + col];
    }
    __syncthreads();
    #pragma unroll
    for (int kk = 0; kk < 64; kk += 32) {
      short8 af[4], bfr[4];
      #pragma unroll
      for (int i = 0; i < 4; ++i)
        af[i] = *(short8*)&As[(wr * 64 + i * 16 + r16) * 64 + kk + khalf];
      #pragma unroll
      for (int j = 0; j < 4; ++j)
        bfr[j] = *(short8*)&Bs[(wc * 64 + j * 16 + r16) * 64 + kk + khalf];
      #pragma unroll
      for (int i = 0; i < 4; ++i)
        #pragma unroll
        for (int j = 0; j < 4; ++j)
          acc[i][j] = __builtin_amdgcn_mfma_f32_16x16x32_bf16(af[i], bfr[j], acc[i][j], 0, 0, 0);
    }
  }
  #pragma unroll
  for (int i = 0; i < 4; ++i)
    #pragma unroll
    for (int j = 0; j < 4; ++j)
      #pragma unroll
      for (int q = 0; q < 4; ++q) {
        int m = m0 + wr * 64 + i * 16 + ((lane >> 4) * 4 + q);
        int n = n0 + wc * 64 + j * 16 + (lane & 15);
        out[(size_t)(m & 7) * 8192000 + (size_t)(m >> 3) * 32000 + n] =
            acc[i][j][q] + bias[n];
      }
}

extern "C" void kernel_launch(void* const* d_in, const int* in_sizes, int n_in,
                              void* d_out, int out_size, void* d_ws, size_t ws_size,
                              hipStream_t stream) {
  (void)in_sizes; (void)n_in; (void)out_size; (void)ws_size;
  char* wsb = (char*)d_ws;
  size_t off = 0;
  auto take = [&](size_t bytes) -> void* {
    void* p = wsb + off;
    off += (bytes + 1023) & ~(size_t)1023;
    return p;
  };
  int* cnt      = (int*)take((size_t)2 * 8 * 32 * 4);      // per-plane gate counters
  int* scnt     = (int*)take((size_t)2 * 8 * 32 * 4);      // per-plane stats counters
  float* statsA = (float*)take((size_t)2 * 2 * 24 * 16 * 4); // [pl][par][row][rep*2]
  float* hlR    = (float*)take((size_t)4 * 8 * 1024 * 4);  // h_l x4 replicas
  float* hhR    = (float*)take((size_t)4 * 8 * 768 * 4);   // h_h x4 replicas
  size_t state_bytes = off;                                // ~238 KB -> memset
  __hip_bfloat16* hist = (__hip_bfloat16*)take((size_t)2048 * 768 * 2);
  float* WiT    = (float*)take((size_t)3 * 1024 * 1536 * 4);
  float* hWiT   = (float*)take((size_t)3 * 768 * 1024 * 4);
  float* hWhT   = (float*)take((size_t)3 * 768 * 768 * 4);
  __hip_bfloat16* WoutT = (__hip_bfloat16*)take((size_t)32000 * 768 * 2);

  hipMemsetAsync(d_ws, 0, state_bytes, stream);  // cnt/scnt/statsA/hlR/hhR = 0

  wout_t<<<dim3(500, 12), 256, 0, stream>>>((const float*)d_in[20], WoutT);

  PArgs A;
  A.ids = (const int*)d_in[0];   A.emb = (const float*)d_in[1];
  A.lng = (const float*)d_in[2]; A.lnb = (const float*)d_in[3];
  A.lWi = (const float*)d_in[4]; A.lbi = (const float*)d_in[5];
  A.lWh = (const float*)d_in[6]; A.lbh = (const float*)d_in[7];
  A.llig = (const float*)d_in[8];  A.llib = (const float*)d_in[9];
  A.llhg = (const float*)d_in[10]; A.llhb = (const float*)d_in[11];
  A.hWi = (const float*)d_in[12];  A.hbi = (const float*)d_in[13];
  A.hWh = (const float*)d_in[14];  A.hbh = (const float*)d_in[15];
  A.hlig = (const float*)d_in[16]; A.hlib = (const float*)d_in[17];
  A.hlhg = (const float*)d_in[18]; A.hlhb = (const float*)d_in[19];
  A.cnt = cnt; A.scnt = scnt; A.statsA = statsA;
  A.hlR = hlR; A.hhR = hhR;
  A.hist = hist; A.WiT = WiT; A.hWiT = hWiT; A.hWhT = hWhT;

  hrm_recur<<<NWG, NTH, 0, stream>>>(A);

  logits_gemm<<<dim3(250, 16), 256, 0, stream>>>(hist, WoutT,
                                                 (const float*)d_in[21],
                                                 (float*)d_out);
}

// Round 13
// 59724.536 us; speedup vs baseline: 1.4299x; 1.4299x over previous
//
#include <hip/hip_runtime.h>
#include <hip/hip_bf16.h>

// HRM-LM on MI355X — 2-plane batch-split pipeline (round-11 base) with
// front-loaded staging and merged gate-wait. Batch rows 0-3 = plane A,
// 4-7 = plane B (independent recurrences, shared LDS-resident weights).
// 128 worker WGs + 2 stats masters. Per round: waitAB (one poll, both
// planes) -> stage ALL planes (1-2 batched sc1 asm blocks; hl->Bb, hh->Bh)
// -> [gemm A, stats A, arrive A] [gemm B, stats B, arrive B] -> [poll A,
// gate A] [poll B, gate B]. Master-A reduce hidden under worker B-compute.
// xi = XW (x@Wi_x per token, local) + h_h@Wi_h. Logits: deferred bf16 MFMA.

#define NWG 128
#define NTH 256
#define EPSV 1e-5f
#define NROUND 4608

typedef __attribute__((ext_vector_type(4))) float f32x4;
typedef __attribute__((ext_vector_type(8))) short short8;
typedef unsigned long long u64;

struct PArgs {
  const int* ids; const float* emb; const float* lng; const float* lnb;
  const float* lWi; const float* lbi; const float* lWh; const float* lbh;
  const float* llig; const float* llib; const float* llhg; const float* llhb;
  const float* hWi; const float* hbi; const float* hWh; const float* hbh;
  const float* hlig; const float* hlib; const float* hlhg; const float* hlhb;
  int* arr; int* rel; int* cnt; u64* sredG; u64* statsG; float* hlR; float* hhR;
  __hip_bfloat16* hist; float* WiT; float* hWiT; float* hWhT;
};

__device__ __forceinline__ float sigm(float x) { return 1.f / (1.f + __expf(-x)); }
__device__ __forceinline__ float tanh_f(float x) {
  x = fminf(15.f, fmaxf(-15.f, x));
  float e = __expf(2.f * x);
  return (e - 1.f) / (e + 1.f);
}
__device__ __forceinline__ int aldi(const int* p) {
  return __hip_atomic_load(p, __ATOMIC_RELAXED, __HIP_MEMORY_SCOPE_AGENT);
}
__device__ __forceinline__ u64 aldu(const u64* p) {
  return __hip_atomic_load(p, __ATOMIC_RELAXED, __HIP_MEMORY_SCOPE_AGENT);
}
__device__ __forceinline__ void asti(int* p, int v) {
  __hip_atomic_store(p, v, __ATOMIC_RELAXED, __HIP_MEMORY_SCOPE_AGENT);
}
__device__ __forceinline__ u64 pk2(float a, float b) {
  union { u64 u; float f[2]; } c; c.f[0] = a; c.f[1] = b; return c.u;
}
__device__ __forceinline__ void astu(u64* p, u64 v) {
  __hip_atomic_store(p, v, __ATOMIC_RELAXED, __HIP_MEMORY_SCOPE_AGENT);
}
__device__ __forceinline__ void ast(float* p, float v) {
  __hip_atomic_store(p, v, __ATOMIC_RELAXED, __HIP_MEMORY_SCOPE_AGENT);
}
// batched 16B sc1 loads; s_waitcnt INSIDE asm -> outputs valid at asm exit
__device__ __forceinline__ void ald4x8(const float* p0, const float* p1,
                                       const float* p2, const float* p3,
                                       const float* p4, const float* p5,
                                       const float* p6, const float* p7,
                                       float4& a, float4& b, float4& c, float4& d,
                                       float4& e, float4& f, float4& g, float4& h) {
  asm volatile(
      "global_load_dwordx4 %0, %8, off sc1\n\t"
      "global_load_dwordx4 %1, %9, off sc1\n\t"
      "global_load_dwordx4 %2, %10, off sc1\n\t"
      "global_load_dwordx4 %3, %11, off sc1\n\t"
      "global_load_dwordx4 %4, %12, off sc1\n\t"
      "global_load_dwordx4 %5, %13, off sc1\n\t"
      "global_load_dwordx4 %6, %14, off sc1\n\t"
      "global_load_dwordx4 %7, %15, off sc1\n\t"
      "s_waitcnt vmcnt(0)"
      : "=&v"(a), "=&v"(b), "=&v"(c), "=&v"(d),
        "=&v"(e), "=&v"(f), "=&v"(g), "=&v"(h)
      : "v"(p0), "v"(p1), "v"(p2), "v"(p3),
        "v"(p4), "v"(p5), "v"(p6), "v"(p7)
      : "memory");
}
__device__ __forceinline__ void ald4x6(const float* p0, const float* p1,
                                       const float* p2, const float* p3,
                                       const float* p4, const float* p5,
                                       float4& a, float4& b, float4& c,
                                       float4& d, float4& e, float4& f) {
  asm volatile(
      "global_load_dwordx4 %0, %6, off sc1\n\t"
      "global_load_dwordx4 %1, %7, off sc1\n\t"
      "global_load_dwordx4 %2, %8, off sc1\n\t"
      "global_load_dwordx4 %3, %9, off sc1\n\t"
      "global_load_dwordx4 %4, %10, off sc1\n\t"
      "global_load_dwordx4 %5, %11, off sc1\n\t"
      "s_waitcnt vmcnt(0)"
      : "=&v"(a), "=&v"(b), "=&v"(c), "=&v"(d), "=&v"(e), "=&v"(f)
      : "v"(p0), "v"(p1), "v"(p2), "v"(p3), "v"(p4), "v"(p5)
      : "memory");
}

__global__ void __launch_bounds__(NTH) hrm_recur(PArgs P) {
  __shared__ float WhS[24 * 1024];   // low_Wh slice [c][k]           96 KB
  __shared__ float Bb[8 * 1024];     // staged h_l, rows 0-3 A, 4-7 B 32 KB
  __shared__ float Bh[8 * 768];      // staged h_h, rows 0-3 A, 4-7 B 24 KB
  __shared__ float XW[24 * 8];       // x @ Wi_x for own 24 cols (per token)
  __shared__ float xiNs[24 * 8];     // normalized xi, kept across inner iters
  __shared__ float stg[2 * 24 * 8];  // raw GEMM outputs (both planes coexist)
  __shared__ float sred[96];         // (m, rs) per (set,g,b)
  __shared__ float xm[8], xrs[8];
  __shared__ float mbuf[96][4];      // master reduce buffer
  __shared__ int idsh[8];
  __shared__ int okf;

  const int tid = threadIdx.x;

  // ================= stats masters (blocks NWG, NWG+1) =================
  if (blockIdx.x >= NWG) {
    const int pl = blockIdx.x - NWG;
    #pragma unroll 1
    for (int r = 1; r <= NROUND; ++r) {
      if (tid < 64) {
        const u64* ap = (const u64*)(P.arr + pl * 128) + tid;
        int lim = 1 << 22, g1 = 1;
        for (;;) {
          u64 v = aldu(ap);
          int a0 = (int)(unsigned)(v & 0xffffffffull);
          int a1 = (int)(unsigned)(v >> 32);
          if (__all(a0 >= r && a1 >= r)) break;
          if (--lim == 0) { g1 = 0; break; }
          __builtin_amdgcn_s_sleep(1);
        }
        if (tid == 0) okf = g1;
      }
      __syncthreads();
      if (!okf) {
        if (tid < 8) asti(P.rel + pl * 128 + tid * 16, 1 << 30);
        return;
      }
      const int ph = (r - 1) % 6;
      const bool full = (ph == 0 || ph == 5);
      const int lo = pl * 24 + (full ? 0 : 12);
      const int n  = full ? 24 : 12;
      const float invD = (ph == 5) ? (1.f / 768.f) : (1.f / 1024.f);
      const int par = r & 1;
      if (tid < (n >> 1) * 8) {            // (row-pair, wg-bucket) lanes
        int rp = (lo >> 1) + (tid >> 3), q = tid & 7;
        const float* fb = (const float*)(P.statsG + (size_t)par * 128 * 48);
        float4 s; s.x = 0.f; s.y = 0.f; s.z = 0.f; s.w = 0.f;
        #pragma unroll
        for (int blk = 0; blk < 2; ++blk) {
          int w0 = q * 16 + blk * 8;
          float4 t0,t1,t2,t3,t4,t5,t6,t7;
          ald4x8(fb + (size_t)(w0+0)*96 + rp*4, fb + (size_t)(w0+1)*96 + rp*4,
                 fb + (size_t)(w0+2)*96 + rp*4, fb + (size_t)(w0+3)*96 + rp*4,
                 fb + (size_t)(w0+4)*96 + rp*4, fb + (size_t)(w0+5)*96 + rp*4,
                 fb + (size_t)(w0+6)*96 + rp*4, fb + (size_t)(w0+7)*96 + rp*4,
                 t0,t1,t2,t3,t4,t5,t6,t7);
          s.x += t0.x+t1.x+t2.x+t3.x+t4.x+t5.x+t6.x+t7.x;
          s.y += t0.y+t1.y+t2.y+t3.y+t4.y+t5.y+t6.y+t7.y;
          s.z += t0.z+t1.z+t2.z+t3.z+t4.z+t5.z+t6.z+t7.z;
          s.w += t0.w+t1.w+t2.w+t3.w+t4.w+t5.w+t6.w+t7.w;
        }
        mbuf[tid][0] = s.x; mbuf[tid][1] = s.y; mbuf[tid][2] = s.z; mbuf[tid][3] = s.w;
      }
      __syncthreads();
      if (tid < n) {
        int rpl = tid >> 1, comp = tid & 1;
        float s1 = 0.f, s2 = 0.f;
        #pragma unroll
        for (int q = 0; q < 8; ++q) {
          s1 += mbuf[rpl * 8 + q][comp * 2 + 0];
          s2 += mbuf[rpl * 8 + q][comp * 2 + 1];
        }
        float m = s1 * invD;
        float rs = rsqrtf(s2 * invD - m * m + EPSV);
        astu(P.sredG + (size_t)pl * 96 + (size_t)par * 48 + lo + tid, pk2(m, rs));
      }
      asm volatile("s_waitcnt vmcnt(0)" ::: "memory");   // payload at LLC
      __syncthreads();
      if (tid < 8) asti(P.rel + pl * 128 + tid * 16, r);
    }
    return;
  }

  // ================================ WORKER ================================
  const int wg = blockIdx.x;
  const int ks = tid & 31, cg = tid >> 5;
  const int lj8 = wg * 8, lj6 = wg * 6;
  const int rep = wg & 3;

  auto arriveA = [&](int pl, int r) {
    asm volatile("s_waitcnt vmcnt(0)" ::: "memory");
    __syncthreads();
    if (tid == 0) asti(P.arr + pl * 128 + wg, r);
  };
  // sync-A release poll (1 lane) + one-shot stats read
  auto pollRel = [&](int pl, int r, bool full) -> bool {
    if (tid == 0) {
      const int* rp = P.rel + pl * 128 + (wg & 7) * 16;
      int lim = 1 << 22, v = 0;
      do {
        v = aldi(rp);
        if (v >= r) break;
        __builtin_amdgcn_s_sleep(1);
      } while (--lim);
      okf = (lim != 0 && v < (1 << 29)) ? 1 : 0;
    }
    __syncthreads();
    if (okf) {
      int lo = pl * 24 + (full ? 0 : 12);
      int n  = full ? 24 : 12;
      if (tid < n) {
        int row = lo + tid;
        union { u64 u; float f[2]; } c;
        c.u = aldu(P.sredG + (size_t)pl * 96 + (size_t)(r & 1) * 48 + row);
        int local = row - pl * 24;
        int set = local / 12, rem = local % 12, g = rem >> 2, bq = rem & 3;
        int b = pl * 4 + bq;
        sred[set * 48 + g * 16 + b * 2] = c.f[0];
        sred[set * 48 + g * 16 + b * 2 + 1] = c.f[1];
      }
      __syncthreads();
    }
    return okf != 0;
  };
  // merged gate-wait: both planes' cumulative counters in one poll loop
  auto waitAB = [&](int target) -> bool {
    if (tid < 64) {
      bool active = tid < 16;
      int pl = (tid >> 3) & 1, idx = tid & 7;
      const int* cp = P.cnt + (active ? (pl * 256 + idx * 32) : 0);
      int lim = 1 << 22;
      for (;;) {
        int v = active ? aldi(cp) : 0;
        v += __shfl_xor(v, 1);
        v += __shfl_xor(v, 2);
        v += __shfl_xor(v, 4);
        int sumA = __shfl(v, 0);
        int sumB = __shfl(v, 8);
        if (sumA >= target && sumB >= target) break;
        if (--lim == 0) break;
        __builtin_amdgcn_s_sleep(2);
      }
      if (tid == 0) okf = (lim != 0) ? 1 : 0;
    }
    __syncthreads();
    return okf != 0;
  };
  auto gate_commit = [&](int pl) {
    asm volatile("s_waitcnt vmcnt(0)" ::: "memory");
    if (tid == 0)
      __hip_atomic_fetch_add(P.cnt + pl * 256 + (size_t)(wg & 7) * 32, 1,
                             __ATOMIC_RELAXED, __HIP_MEMORY_SCOPE_AGENT);
  };

  // ---- staging: ALL planes in one batched asm block each ----
  auto stage_all_hl = [&]() {     // 8 rows x 1024 -> Bb
    const float* base = P.hlR + (size_t)rep * 8192 + tid * 4;
    float4 t0,t1,t2,t3,t4,t5,t6,t7;
    ald4x8(base + 0*1024, base + 1*1024, base + 2*1024, base + 3*1024,
           base + 4*1024, base + 5*1024, base + 6*1024, base + 7*1024,
           t0,t1,t2,t3,t4,t5,t6,t7);
    float* db = &Bb[tid * 4];
    *(float4*)&db[0*1024] = t0; *(float4*)&db[1*1024] = t1;
    *(float4*)&db[2*1024] = t2; *(float4*)&db[3*1024] = t3;
    *(float4*)&db[4*1024] = t4; *(float4*)&db[5*1024] = t5;
    *(float4*)&db[6*1024] = t6; *(float4*)&db[7*1024] = t7;
  };
  auto stage_all_hh = [&]() {     // 8 rows x 768 -> Bh
    const float* base = P.hhR + (size_t)rep * 6144;
    int bi[6], ki[6];
    #pragma unroll
    for (int i = 0; i < 6; ++i) {
      int c = i * 256 + tid; int bq = c / 192; int k = (c - bq * 192) * 4;
      bi[i] = bq; ki[i] = k;
    }
    float4 t0,t1,t2,t3,t4,t5;
    ald4x6(base + bi[0]*768 + ki[0], base + bi[1]*768 + ki[1],
           base + bi[2]*768 + ki[2], base + bi[3]*768 + ki[3],
           base + bi[4]*768 + ki[4], base + bi[5]*768 + ki[5],
           t0,t1,t2,t3,t4,t5);
    *(float4*)&Bh[bi[0]*768 + ki[0]] = t0; *(float4*)&Bh[bi[1]*768 + ki[1]] = t1;
    *(float4*)&Bh[bi[2]*768 + ki[2]] = t2; *(float4*)&Bh[bi[3]*768 + ki[3]] = t3;
    *(float4*)&Bh[bi[4]*768 + ki[4]] = t4; *(float4*)&Bh[bi[5]*768 + ki[5]] = t5;
  };

  auto gemm_lowh = [&](int pl, float (&acc)[3][4]) {
    const int c0 = cg * 3;
    const float* w0p = &WhS[(c0 + 0) * 1024];
    const float* w1p = &WhS[(c0 + 1) * 1024];
    const float* w2p = &WhS[(c0 + 2) * 1024];
    const float* hb = &Bb[pl * 4096];
    #pragma unroll
    for (int i = 0; i < 8; ++i) {
      int k = i * 128 + ks * 4;
      float4 w0 = *(const float4*)&w0p[k];
      float4 w1 = *(const float4*)&w1p[k];
      float4 w2 = *(const float4*)&w2p[k];
      #pragma unroll
      for (int bq = 0; bq < 4; ++bq) {
        float4 h = *(const float4*)&hb[bq * 1024 + k];
        acc[0][bq] += w0.x*h.x + w0.y*h.y + w0.z*h.z + w0.w*h.w;
        acc[1][bq] += w1.x*h.x + w1.y*h.y + w1.z*h.z + w1.w*h.w;
        acc[2][bq] += w2.x*h.x + w2.y*h.y + w2.z*h.z + w2.w*h.w;
      }
    }
  };
  auto gemm_xih = [&](int pl, float (&acc)[3][4]) {   // K=768 over Bh
    const float* wp[3];
    #pragma unroll
    for (int cc = 0; cc < 3; ++cc) {
      int c = cg * 3 + cc; int g = c >> 3, jj = c & 7;
      wp[cc] = P.WiT + ((size_t)g * 1024 + lj8 + jj) * 1536 + 768;
    }
    const float* hb = &Bh[pl * 3072];
    #pragma unroll
    for (int i = 0; i < 6; ++i) {
      int k = i * 128 + ks * 4;
      float4 w0 = *(const float4*)&wp[0][k];
      float4 w1 = *(const float4*)&wp[1][k];
      float4 w2 = *(const float4*)&wp[2][k];
      #pragma unroll
      for (int bq = 0; bq < 4; ++bq) {
        float4 h = *(const float4*)&hb[bq * 768 + k];
        acc[0][bq] += w0.x*h.x + w0.y*h.y + w0.z*h.z + w0.w*h.w;
        acc[1][bq] += w1.x*h.x + w1.y*h.y + w1.z*h.z + w1.w*h.w;
        acc[2][bq] += w2.x*h.x + w2.y*h.y + w2.z*h.z + w2.w*h.w;
      }
    }
  };
  auto gemm_hxi = [&](int pl, float (&acc)[3][4]) {  // K=1024 over Bb=hl
    if (cg >= 6) return;
    const float* wp[3];
    #pragma unroll
    for (int cc = 0; cc < 3; ++cc) {
      int c = cg * 3 + cc; int g = c / 6, jj = c % 6;
      wp[cc] = P.hWiT + ((size_t)g * 768 + lj6 + jj) * 1024;
    }
    const float* hb = &Bb[pl * 4096];
    #pragma unroll
    for (int i = 0; i < 8; ++i) {
      int k = i * 128 + ks * 4;
      float4 w0 = *(const float4*)&wp[0][k];
      float4 w1 = *(const float4*)&wp[1][k];
      float4 w2 = *(const float4*)&wp[2][k];
      #pragma unroll
      for (int bq = 0; bq < 4; ++bq) {
        float4 h = *(const float4*)&hb[bq * 1024 + k];
        acc[0][bq] += w0.x*h.x + w0.y*h.y + w0.z*h.z + w0.w*h.w;
        acc[1][bq] += w1.x*h.x + w1.y*h.y + w1.z*h.z + w1.w*h.w;
        acc[2][bq] += w2.x*h.x + w2.y*h.y + w2.z*h.z + w2.w*h.w;
      }
    }
  };
  auto gemm_hhh = [&](int pl, float (&acc)[3][4]) {  // K=768 over Bh=hh
    if (cg >= 6) return;
    const float* wp[3];
    #pragma unroll
    for (int cc = 0; cc < 3; ++cc) {
      int c = cg * 3 + cc; int g = c / 6, jj = c % 6;
      wp[cc] = P.hWhT + ((size_t)g * 768 + lj6 + jj) * 768;
    }
    const float* hb = &Bh[pl * 3072];
    #pragma unroll
    for (int i = 0; i < 6; ++i) {
      int k = i * 128 + ks * 4;
      float4 w0 = *(const float4*)&wp[0][k];
      float4 w1 = *(const float4*)&wp[1][k];
      float4 w2 = *(const float4*)&wp[2][k];
      #pragma unroll
      for (int bq = 0; bq < 4; ++bq) {
        float4 h = *(const float4*)&hb[bq * 768 + k];
        acc[0][bq] += w0.x*h.x + w0.y*h.y + w0.z*h.z + w0.w*h.w;
        acc[1][bq] += w1.x*h.x + w1.y*h.y + w1.z*h.z + w1.w*h.w;
        acc[2][bq] += w2.x*h.x + w2.y*h.y + w2.z*h.z + w2.w*h.w;
      }
    }
  };

  auto redstage = [&](int pl, float (&acc)[3][4], int set, const float* bias,
                      int dim, int perg, int jb, bool addXW) {
    #pragma unroll
    for (int cc = 0; cc < 3; ++cc)
      #pragma unroll
      for (int bq = 0; bq < 4; ++bq) {
        float v = acc[cc][bq];
        #pragma unroll
        for (int m = 1; m < 32; m <<= 1) v += __shfl_xor(v, m, 64);
        acc[cc][bq] = v;
      }
    if ((tid & 31) == 0) {
      int cgl = tid >> 5;
      #pragma unroll
      for (int cc = 0; cc < 3; ++cc) {
        int c = cgl * 3 + cc;
        if (c < perg * 3) {
          int g = (perg == 8) ? (c >> 3) : (c / 6);
          int jj = (perg == 8) ? (c & 7) : (c % 6);
          float bs = bias[g * dim + jb + jj];
          #pragma unroll
          for (int bq = 0; bq < 4; ++bq) {
            float v = acc[cc][bq] + bs;
            if (addXW) v += XW[c * 8 + pl * 4 + bq];
            stg[set * 192 + c * 8 + pl * 4 + bq] = v;
          }
        }
      }
    }
  };

  // private (s1,s2) partial -> statsG[par][wg][row], row = pl*24+set*12+g*4+bq
  auto stats_put = [&](int pl, int par, int set, int perg) {
    if (tid < 12) {
      int g = tid >> 2, bq = tid & 3;
      float s1 = 0.f, s2 = 0.f;
      for (int jj = 0; jj < perg; ++jj) {
        float v = stg[set * 192 + (g * perg + jj) * 8 + pl * 4 + bq];
        s1 += v; s2 += v * v;
      }
      int row = pl * 24 + set * 12 + g * 4 + bq;
      astu(P.statsG + ((size_t)par * 128 + wg) * 48 + row, pk2(s1, s2));
    }
  };

  auto gate_low = [&](int pl, bool isA) {
    if (tid < 32) {
      int jj = tid & 7, bq = tid >> 3; int b = pl * 4 + bq; int j = lj8 + jj;
      float xin[3], hin[3];
      #pragma unroll
      for (int g = 0; g < 3; ++g) {
        int c = g * 8 + jj;
        if (isA) {
          float m = sred[g * 16 + b * 2], rs = sred[g * 16 + b * 2 + 1];
          float v = (stg[c * 8 + b] - m) * rs * P.llig[g * 1024 + j] + P.llib[g * 1024 + j];
          xiNs[c * 8 + b] = v; xin[g] = v;
        } else {
          xin[g] = xiNs[c * 8 + b];
        }
        float m2 = sred[48 + g * 16 + b * 2], rs2 = sred[48 + g * 16 + b * 2 + 1];
        hin[g] = (stg[192 + c * 8 + b] - m2) * rs2 * P.llhg[g * 1024 + j] + P.llhb[g * 1024 + j];
      }
      float rg = sigm(xin[0] + hin[0]);
      float zg = sigm(xin[1] + hin[1]);
      float ng = tanh_f(xin[2] + rg * hin[2]);
      float hold = Bb[b * 1024 + j];
      float hv = (1.f - zg) * ng + zg * hold;
      #pragma unroll
      for (int rp = 0; rp < 4; ++rp) ast(&P.hlR[rp * 8192 + b * 1024 + j], hv);
    }
  };

  auto gate_high = [&](int pl, int t, int nn) {
    if (tid < 24) {
      int jj = tid % 6, bq = tid / 6; int b = pl * 4 + bq; int j = lj6 + jj;
      float xin[3], hin[3];
      #pragma unroll
      for (int g = 0; g < 3; ++g) {
        int c = g * 6 + jj;
        float m = sred[g * 16 + b * 2], rs = sred[g * 16 + b * 2 + 1];
        xin[g] = (stg[c * 8 + b] - m) * rs * P.hlig[g * 768 + j] + P.hlib[g * 768 + j];
        float m2 = sred[48 + g * 16 + b * 2], rs2 = sred[48 + g * 16 + b * 2 + 1];
        hin[g] = (stg[192 + c * 8 + b] - m2) * rs2 * P.hlhg[g * 768 + j] + P.hlhb[g * 768 + j];
      }
      float rg = sigm(xin[0] + hin[0]);
      float zg = sigm(xin[1] + hin[1]);
      float ng = tanh_f(xin[2] + rg * hin[2]);
      float hold = Bh[b * 768 + j];
      float hv = (1.f - zg) * ng + zg * hold;
      #pragma unroll
      for (int rp = 0; rp < 4; ++rp) ast(&P.hhR[rp * 6144 + b * 768 + j], hv);
      if (nn == 2) P.hist[((size_t)t * 8 + b) * 768 + j] = __float2bfloat16(hv);
    }
  };

  // per token: LN(x) stats + XW = LN(x) @ Wi_x (own 24 cols, all 8 b, local)
  auto xfun = [&](int tt) {
    int bq = tid >> 5, u = tid & 31;
    if (tid < 8) idsh[tid] = P.ids[tid * 256 + tt];
    int id = P.ids[bq * 256 + tt];
    const float* e = P.emb + (size_t)id * 768;
    float s1 = 0.f, s2 = 0.f;
    #pragma unroll
    for (int q = 0; q < 24; q += 4) {
      float4 v = *(const float4*)&e[u * 24 + q];
      s1 += v.x + v.y + v.z + v.w;
      s2 += v.x*v.x + v.y*v.y + v.z*v.z + v.w*v.w;
    }
    #pragma unroll
    for (int m = 1; m < 32; m <<= 1) { s1 += __shfl_xor(s1, m, 64); s2 += __shfl_xor(s2, m, 64); }
    if (u == 0) { float mm = s1 / 768.f; xm[bq] = mm; xrs[bq] = rsqrtf(s2 / 768.f - mm * mm + EPSV); }
    __syncthreads();
    float acc[3][8] = {};
    const float* wp[3];
    #pragma unroll
    for (int cc = 0; cc < 3; ++cc) {
      int c = cg * 3 + cc; int g = c >> 3, jj = c & 7;
      wp[cc] = P.WiT + ((size_t)g * 1024 + lj8 + jj) * 1536;
    }
    int idv[8];
    #pragma unroll
    for (int bb = 0; bb < 8; ++bb) idv[bb] = idsh[bb];
    #pragma unroll
    for (int i = 0; i < 6; ++i) {
      int k = i * 128 + ks * 4;
      float4 w0 = *(const float4*)&wp[0][k];
      float4 w1 = *(const float4*)&wp[1][k];
      float4 w2 = *(const float4*)&wp[2][k];
      float4 gam = *(const float4*)&P.lng[k];
      float4 bet = *(const float4*)&P.lnb[k];
      #pragma unroll
      for (int bb = 0; bb < 8; ++bb) {
        float4 xv = *(const float4*)&P.emb[(size_t)idv[bb] * 768 + k];
        float4 xn;
        xn.x = (xv.x - xm[bb]) * xrs[bb] * gam.x + bet.x;
        xn.y = (xv.y - xm[bb]) * xrs[bb] * gam.y + bet.y;
        xn.z = (xv.z - xm[bb]) * xrs[bb] * gam.z + bet.z;
        xn.w = (xv.w - xm[bb]) * xrs[bb] * gam.w + bet.w;
        acc[0][bb] += w0.x*xn.x + w0.y*xn.y + w0.z*xn.z + w0.w*xn.w;
        acc[1][bb] += w1.x*xn.x + w1.y*xn.y + w1.z*xn.z + w1.w*xn.w;
        acc[2][bb] += w2.x*xn.x + w2.y*xn.y + w2.z*xn.z + w2.w*xn.w;
      }
    }
    #pragma unroll
    for (int cc = 0; cc < 3; ++cc)
      #pragma unroll
      for (int bb = 0; bb < 8; ++bb) {
        float v = acc[cc][bb];
        #pragma unroll
        for (int m = 1; m < 32; m <<= 1) v += __shfl_xor(v, m, 64);
        acc[cc][bb] = v;
      }
    if ((tid & 31) == 0) {
      int cgl = tid >> 5;
      #pragma unroll
      for (int cc = 0; cc < 3; ++cc)
        #pragma unroll
        for (int bb = 0; bb < 8; ++bb)
          XW[(cgl * 3 + cc) * 8 + bb] = acc[cc][bb];
    }
    __syncthreads();
  };

  // =================== prologue: weight transposes ===================
  #pragma unroll 1
  for (int g = 0; g < 3; ++g)
    for (int it = 0; it < 6; ++it) {   // low_Wi -> WiT[g][j][k]
      int k = it * 256 + tid;
      const float* src = P.lWi + ((size_t)g * 1536 + k) * 1024 + lj8;
      float4 v0 = *(const float4*)src; float4 v1 = *(const float4*)(src + 4);
      float vv[8] = {v0.x, v0.y, v0.z, v0.w, v1.x, v1.y, v1.z, v1.w};
      for (int jj = 0; jj < 8; ++jj)
        P.WiT[((size_t)g * 1024 + lj8 + jj) * 1536 + k] = vv[jj];
    }
  #pragma unroll 1
  for (int g = 0; g < 3; ++g)
    for (int it = 0; it < 4; ++it) {   // high_Wi -> hWiT[g][j][k]
      int k = it * 256 + tid;
      const float* src = P.hWi + ((size_t)g * 1024 + k) * 768 + lj6;
      float2 a = *(const float2*)src, b2v = *(const float2*)(src + 2), c2v = *(const float2*)(src + 4);
      float vv[6] = {a.x, a.y, b2v.x, b2v.y, c2v.x, c2v.y};
      for (int jj = 0; jj < 6; ++jj)
        P.hWiT[((size_t)g * 768 + lj6 + jj) * 1024 + k] = vv[jj];
    }
  #pragma unroll 1
  for (int g = 0; g < 3; ++g)
    for (int it = 0; it < 3; ++it) {   // high_Wh -> hWhT[g][j][k]
      int k = it * 256 + tid;
      const float* src = P.hWh + ((size_t)g * 768 + k) * 768 + lj6;
      float2 a = *(const float2*)src, b2v = *(const float2*)(src + 2), c2v = *(const float2*)(src + 4);
      float vv[6] = {a.x, a.y, b2v.x, b2v.y, c2v.x, c2v.y};
      for (int jj = 0; jj < 6; ++jj)
        P.hWhT[((size_t)g * 768 + lj6 + jj) * 768 + k] = vv[jj];
    }
  #pragma unroll 1
  for (int g = 0; g < 3; ++g)
    for (int it = 0; it < 4; ++it) {   // low_Wh slice -> LDS
      int k = it * 256 + tid;
      const float* src = P.lWh + ((size_t)g * 1024 + k) * 1024 + lj8;
      float4 v0 = *(const float4*)src; float4 v1 = *(const float4*)(src + 4);
      float vv[8] = {v0.x, v0.y, v0.z, v0.w, v1.x, v1.y, v1.z, v1.w};
      for (int jj = 0; jj < 8; ++jj) WhS[(g * 8 + jj) * 1024 + k] = vv[jj];
    }
  __syncthreads();
  xfun(0);

  // =================== main recurrence (2-plane pipeline) ===================
  int r = 1;
  bool alive = true;
  #pragma unroll 1
  for (int t = 0; t < 256 && alive; ++t) {
    #pragma unroll 1
    for (int nn = 0; nn < 3 && alive; ++nn) {
      // ---- round A: xi (XW + hh@Wi_h) + lowh ----
      {
        alive = waitAB(NWG * (r - 1)); if (!alive) break;
        stage_all_hh(); stage_all_hl();
        __syncthreads();
        #pragma unroll 1
        for (int pl = 0; pl < 2; ++pl) {
          float aX[3][4] = {};
          gemm_xih(pl, aX);
          redstage(pl, aX, 0, P.lbi, 1024, 8, lj8, true);
          float aH[3][4] = {};
          gemm_lowh(pl, aH);
          redstage(pl, aH, 1, P.lbh, 1024, 8, lj8, false);
          __syncthreads();
          stats_put(pl, r & 1, 0, 8); stats_put(pl, r & 1, 1, 8);
          arriveA(pl, r);
        }
        #pragma unroll 1
        for (int pl = 0; pl < 2; ++pl) {
          alive = pollRel(pl, r, true); if (!alive) break;
          gate_low(pl, true);
          gate_commit(pl);
        }
        if (!alive) break;
        ++r;
      }
      // ---- inner iterations 2..5 ----
      #pragma unroll 1
      for (int it = 1; it < 5 && alive; ++it) {
        alive = waitAB(NWG * (r - 1)); if (!alive) break;
        stage_all_hl();
        __syncthreads();
        #pragma unroll 1
        for (int pl = 0; pl < 2; ++pl) {
          float a2[3][4] = {};
          gemm_lowh(pl, a2);
          redstage(pl, a2, 1, P.lbh, 1024, 8, lj8, false);
          __syncthreads();
          stats_put(pl, r & 1, 1, 8);
          arriveA(pl, r);
        }
        #pragma unroll 1
        for (int pl = 0; pl < 2; ++pl) {
          alive = pollRel(pl, r, false); if (!alive) break;
          gate_low(pl, false);
          gate_commit(pl);
        }
        if (!alive) break;
        ++r;
      }
      if (!alive) break;
      // ---- high GRU round ----
      {
        alive = waitAB(NWG * (r - 1)); if (!alive) break;
        stage_all_hl(); stage_all_hh();
        __syncthreads();
        #pragma unroll 1
        for (int pl = 0; pl < 2; ++pl) {
          float aX[3][4] = {};
          gemm_hxi(pl, aX);
          redstage(pl, aX, 0, P.hbi, 768, 6, lj6, false);
          float aH[3][4] = {};
          gemm_hhh(pl, aH);
          redstage(pl, aH, 1, P.hbh, 768, 6, lj6, false);
          __syncthreads();
          stats_put(pl, r & 1, 0, 6); stats_put(pl, r & 1, 1, 6);
          arriveA(pl, r);
        }
        #pragma unroll 1
        for (int pl = 0; pl < 2; ++pl) {
          alive = pollRel(pl, r, true); if (!alive) break;
          gate_high(pl, t, nn);
          gate_commit(pl);
        }
        if (!alive) break;
        ++r;
        if (nn == 2 && t < 255) { __syncthreads(); xfun(t + 1); }
      }
    }
  }
}

// =================== Wout transpose + bf16 convert ===================
__global__ void __launch_bounds__(256) wout_t(const float* __restrict__ W,
                                              __hip_bfloat16* __restrict__ WT) {
  __shared__ float T[64][65];
  int n0 = blockIdx.x * 64, k0 = blockIdx.y * 64;
  int tid = threadIdx.x;
  int lane16 = tid & 15, grp = tid >> 4;
  #pragma unroll
  for (int i = 0; i < 4; ++i) {
    int kl = i * 16 + grp; int nl = lane16 * 4;
    float4 v = *(const float4*)&W[(size_t)(k0 + kl) * 32000 + n0 + nl];
    T[kl][nl] = v.x; T[kl][nl + 1] = v.y; T[kl][nl + 2] = v.z; T[kl][nl + 3] = v.w;
  }
  __syncthreads();
  #pragma unroll
  for (int i = 0; i < 4; ++i) {
    int nl = i * 16 + grp; int kl = lane16 * 4;
    union { ushort4 v; __hip_bfloat16 h[4]; } u;
    for (int q = 0; q < 4; ++q) u.h[q] = __float2bfloat16(T[kl + q][nl]);
    *(ushort4*)&WT[(size_t)(n0 + nl) * 768 + k0 + kl] = u.v;
  }
}

// =================== logits GEMM: [2048,768] x [768,32000]^T-stored ===================
__global__ void __launch_bounds__(256) logits_gemm(const __hip_bfloat16* __restrict__ Ah,
                                                   const __hip_bfloat16* __restrict__ Bt,
                                                   const float* __restrict__ bias,
                                                   float* __restrict__ out) {
  __shared__ short As[128 * 64];
  __shared__ short Bs[128 * 64];
  int m0 = blockIdx.y * 128, n0 = blockIdx.x * 128;
  int tid = threadIdx.x, lane = tid & 63, w = tid >> 6;
  int wr = w >> 1, wc = w & 1;
  int r16 = lane & 15, khalf = (lane >> 4) * 8;
  f32x4 acc[4][4];
  #pragma unroll
  for (int i = 0; i < 4; ++i)
    #pragma unroll
    for (int j = 0; j < 4; ++j)
      #pragma unroll
      for (int q = 0; q < 4; ++q) acc[i][j][q] = 0.f;

  for (int kt = 0; kt < 12; ++kt) {
    int k0 = kt * 64;
    __syncthreads();
    #pragma unroll
    for (int it = 0; it < 4; ++it) {
      int f = it * 2048 + tid * 8; int row = f >> 6, col = f & 63;
      *(uint4*)&As[f] = *(const uint4*)&Ah[(size_t)(m0 + row) * 768 + k0 + col];
      *(uint4*)&Bs[f] = *(const uint4*)&Bt[(size_t)(n0 + row) * 768 + k0 + col];
    }
    __syncthreads();
    #pragma unroll
    for (int kk = 0; kk < 64; kk += 32) {
      short8 af[4], bfr[4];
      #pragma unroll
      for (int i = 0; i < 4; ++i)
        af[i] = *(short8*)&As[(wr * 64 + i * 16 + r16) * 64 + kk + khalf];
      #pragma unroll
      for (int j = 0; j < 4; ++j)
        bfr[j] = *(short8*)&Bs[(wc * 64 + j * 16 + r16) * 64 + kk + khalf];
      #pragma unroll
      for (int i = 0; i < 4; ++i)
        #pragma unroll
        for (int j = 0; j < 4; ++j)
          acc[i][j] = __builtin_amdgcn_mfma_f32_16x16x32_bf16(af[i], bfr[j], acc[i][j], 0, 0, 0);
    }
  }
  #pragma unroll
  for (int i = 0; i < 4; ++i)
    #pragma unroll
    for (int j = 0; j < 4; ++j)
      #pragma unroll
      for (int q = 0; q < 4; ++q) {
        int m = m0 + wr * 64 + i * 16 + ((lane >> 4) * 4 + q);
        int n = n0 + wc * 64 + j * 16 + (lane & 15);
        out[(size_t)(m & 7) * 8192000 + (size_t)(m >> 3) * 32000 + n] =
            acc[i][j][q] + bias[n];
      }
}

extern "C" void kernel_launch(void* const* d_in, const int* in_sizes, int n_in,
                              void* d_out, int out_size, void* d_ws, size_t ws_size,
                              hipStream_t stream) {
  (void)in_sizes; (void)n_in; (void)out_size; (void)ws_size;
  char* wsb = (char*)d_ws;
  size_t off = 0;
  auto take = [&](size_t bytes) -> void* {
    void* p = wsb + off;
    off += (bytes + 1023) & ~(size_t)1023;
    return p;
  };
  int* arr    = (int*)take((size_t)2 * 128 * 4);         // per-plane arrivals
  int* rel    = (int*)take((size_t)2 * 128 * 4);         // per-plane release lines
  int* cnt    = (int*)take((size_t)2 * 8 * 32 * 4);      // per-plane gate counters
  u64* sredG  = (u64*)take((size_t)2 * 2 * 48 * 8);      // per-plane (m,rs) payload
  float* hlR  = (float*)take((size_t)4 * 8 * 1024 * 4);  // h_l x4 replicas
  float* hhR  = (float*)take((size_t)4 * 8 * 768 * 4);   // h_h x4 replicas
  size_t state_bytes = off;                              // ~235 KB -> memset
  u64* statsG = (u64*)take((size_t)2 * 128 * 48 * 8);    // private stats partials
  __hip_bfloat16* hist = (__hip_bfloat16*)take((size_t)2048 * 768 * 2);
  float* WiT  = (float*)take((size_t)3 * 1024 * 1536 * 4);
  float* hWiT = (float*)take((size_t)3 * 768 * 1024 * 4);
  float* hWhT = (float*)take((size_t)3 * 768 * 768 * 4);
  __hip_bfloat16* WoutT = (__hip_bfloat16*)take((size_t)32000 * 768 * 2);

  hipMemsetAsync(d_ws, 0, state_bytes, stream);  // arr/rel/cnt/sredG/hlR/hhR = 0

  wout_t<<<dim3(500, 12), 256, 0, stream>>>((const float*)d_in[20], WoutT);

  PArgs A;
  A.ids = (const int*)d_in[0];   A.emb = (const float*)d_in[1];
  A.lng = (const float*)d_in[2]; A.lnb = (const float*)d_in[3];
  A.lWi = (const float*)d_in[4]; A.lbi = (const float*)d_in[5];
  A.lWh = (const float*)d_in[6]; A.lbh = (const float*)d_in[7];
  A.llig = (const float*)d_in[8];  A.llib = (const float*)d_in[9];
  A.llhg = (const float*)d_in[10]; A.llhb = (const float*)d_in[11];
  A.hWi = (const float*)d_in[12];  A.hbi = (const float*)d_in[13];
  A.hWh = (const float*)d_in[14];  A.hbh = (const float*)d_in[15];
  A.hlig = (const float*)d_in[16]; A.hlib = (const float*)d_in[17];
  A.hlhg = (const float*)d_in[18]; A.hlhb = (const float*)d_in[19];
  A.arr = arr; A.rel = rel; A.cnt = cnt; A.sredG = sredG; A.statsG = statsG;
  A.hlR = hlR; A.hhR = hhR;
  A.hist = hist; A.WiT = WiT; A.hWiT = hWiT; A.hWhT = hWhT;

  hrm_recur<<<NWG + 2, NTH, 0, stream>>>(A);

  logits_gemm<<<dim3(250, 16), 256, 0, stream>>>(hist, WoutT,
                                                 (const float*)d_in[21],
                                                 (float*)d_out);
}